// Round 1
// baseline (2896.469 us; speedup 1.0000x reference)
//
#include <hip/hip_runtime.h>

#define N_USER 50000
#define N_ITEM 50000
#define N_EDGE 800000
#define D 128

// ---------------------------------------------------------------------------
// Gather rows: out[r] = emb[ids[r]]   (32 threads/row, float4 each)
// ---------------------------------------------------------------------------
__global__ void gather_kernel(const float* __restrict__ emb, const int* __restrict__ ids,
                              float* __restrict__ out, int nRows) {
    int gid = blockIdx.x * blockDim.x + threadIdx.x;
    int row = gid >> 5;
    if (row >= nRows) return;
    int c = (gid & 31) << 2;
    int src = ids[row];
    const float4 v = *reinterpret_cast<const float4*>(emb + (size_t)src * D + c);
    *reinterpret_cast<float4*>(out + (size_t)row * D + c) = v;
}

// ---------------------------------------------------------------------------
// Edge scatter-add: agg[dst] += feat[src]; cnt[dst] += 1
// 32 threads per edge, each handles 4 consecutive dims.
// ---------------------------------------------------------------------------
__global__ void scatter_kernel(const float* __restrict__ feat, const int* __restrict__ esrc,
                               const int* __restrict__ edst, float* __restrict__ agg,
                               float* __restrict__ cnt, int nEdges) {
    int gid = blockIdx.x * blockDim.x + threadIdx.x;
    int e = gid >> 5;
    if (e >= nEdges) return;
    int c = (gid & 31) << 2;
    int s = esrc[e], d = edst[e];
    const float4 v = *reinterpret_cast<const float4*>(feat + (size_t)s * D + c);
    float* p = agg + (size_t)d * D + c;
    unsafeAtomicAdd(p + 0, v.x);
    unsafeAtomicAdd(p + 1, v.y);
    unsafeAtomicAdd(p + 2, v.z);
    unsafeAtomicAdd(p + 3, v.w);
    if ((gid & 31) == 0) unsafeAtomicAdd(cnt + d, 1.0f);
}

// ---------------------------------------------------------------------------
// Fused epilogue: out[m] = (agg[m]/max(cnt[m],1)) @ Wl + x[m] @ Wr + b
// In-place on agg (each block owns its rows; reads before writes).
// M-tile 64, N=128, K=256 (128 agg + 128 x), KC=32 chunks.
// 256 threads: thread computes 8 rows x 4 cols.
// ---------------------------------------------------------------------------
#define BM 64
#define KC 32
#define APAD 68  // 64 + 4 -> rows stay 16B aligned, near-conflict-free

__global__ __launch_bounds__(256) void finish_kernel(
    float* __restrict__ agg_out, const float* __restrict__ xr,
    const float* __restrict__ Wl, const float* __restrict__ Wr,
    const float* __restrict__ bias, const float* __restrict__ cnt, int nRows)
{
    __shared__ __align__(16) float At[KC][APAD];   // transposed A chunk [k][m]
    __shared__ __align__(16) float Wt[KC][D];      // W chunk [k][n]
    __shared__ float scale[BM];

    const int tid = threadIdx.x;
    const int block_row = blockIdx.x * BM;
    const int tn = tid & 31;   // col group: cols 4*tn .. 4*tn+3
    const int tm = tid >> 5;   // row group: rows 8*tm .. 8*tm+7

    if (tid < BM) {
        int r = block_row + tid;
        float c = (r < nRows) ? cnt[r] : 1.0f;
        scale[tid] = 1.0f / fmaxf(c, 1.0f);
    }

    float acc[8][4];
#pragma unroll
    for (int i = 0; i < 8; ++i)
#pragma unroll
        for (int j = 0; j < 4; ++j) acc[i][j] = 0.f;

    for (int kc = 0; kc < 2 * D; kc += KC) {
        __syncthreads();  // LDS reuse + (first iter) scale ready
        // --- load A chunk (64 rows x 32 k), transposed into LDS ---
#pragma unroll
        for (int l = 0; l < 2; ++l) {
            int f = tid + l * 256;       // float4 index in [0,512)
            int m = f >> 3;              // row in tile
            int kq = (f & 7) << 2;       // k offset within chunk
            int gr = block_row + m;
            float4 v = make_float4(0.f, 0.f, 0.f, 0.f);
            if (gr < nRows) {
                int k0 = kc + kq;
                if (k0 < D) {
                    v = *reinterpret_cast<const float4*>(agg_out + (size_t)gr * D + k0);
                    float s = scale[m];
                    v.x *= s; v.y *= s; v.z *= s; v.w *= s;
                } else {
                    v = *reinterpret_cast<const float4*>(xr + (size_t)gr * D + (k0 - D));
                }
            }
            At[kq + 0][m] = v.x;
            At[kq + 1][m] = v.y;
            At[kq + 2][m] = v.z;
            At[kq + 3][m] = v.w;
        }
        // --- load W chunk (32 k x 128 n) ---
        const float* Wsrc = (kc < D) ? (Wl + (size_t)kc * D) : (Wr + (size_t)(kc - D) * D);
#pragma unroll
        for (int l = 0; l < 4; ++l) {
            int f = tid + l * 256;       // float4 index in [0,1024)
            int k = f >> 5;
            int n4 = (f & 31) << 2;
            float4 v = *reinterpret_cast<const float4*>(Wsrc + (size_t)k * D + n4);
            *reinterpret_cast<float4*>(&Wt[k][n4]) = v;
        }
        __syncthreads();
        // --- FMA ---
#pragma unroll
        for (int k = 0; k < KC; ++k) {
            const float4 a0 = *reinterpret_cast<const float4*>(&At[k][tm * 8]);
            const float4 a1 = *reinterpret_cast<const float4*>(&At[k][tm * 8 + 4]);
            const float4 wv = *reinterpret_cast<const float4*>(&Wt[k][tn * 4]);
            const float a[8] = {a0.x, a0.y, a0.z, a0.w, a1.x, a1.y, a1.z, a1.w};
            const float w[4] = {wv.x, wv.y, wv.z, wv.w};
#pragma unroll
            for (int i = 0; i < 8; ++i)
#pragma unroll
                for (int j = 0; j < 4; ++j) acc[i][j] += a[i] * w[j];
        }
    }

    float4 bv = *reinterpret_cast<const float4*>(bias + tn * 4);
#pragma unroll
    for (int i = 0; i < 8; ++i) {
        int r = block_row + tm * 8 + i;
        if (r < nRows) {
            float4 v = make_float4(acc[i][0] + bv.x, acc[i][1] + bv.y,
                                   acc[i][2] + bv.z, acc[i][3] + bv.w);
            *reinterpret_cast<float4*>(agg_out + (size_t)r * D + tn * 4) = v;
        }
    }
}

// ---------------------------------------------------------------------------
extern "C" void kernel_launch(void* const* d_in, const int* in_sizes, int n_in,
                              void* d_out, int out_size, void* d_ws, size_t ws_size,
                              hipStream_t stream) {
    const int*   user_ids = (const int*)d_in[0];
    const float* item_x   = (const float*)d_in[1];
    const int*   edge_ui  = (const int*)d_in[2];
    const int*   edge_iu  = (const int*)d_in[3];
    const float* user_emb = (const float*)d_in[4];
    const float* W_l_ui   = (const float*)d_in[5];
    const float* W_r_ui   = (const float*)d_in[6];
    const float* b_ui     = (const float*)d_in[7];
    const float* W_l_iu   = (const float*)d_in[8];
    const float* W_r_iu   = (const float*)d_in[9];
    const float* b_iu     = (const float*)d_in[10];

    float* out      = (float*)d_out;
    float* out_user = out;                        // agg_iu accumulates here
    float* out_item = out + (size_t)N_USER * D;   // agg_ui accumulates here

    float* x_user = (float*)d_ws;                       // N_USER*D
    float* cnt_ui = x_user + (size_t)N_USER * D;        // N_ITEM
    float* cnt_iu = cnt_ui + N_ITEM;                    // N_USER

    hipMemsetAsync(d_out, 0, sizeof(float) * (size_t)(N_USER + N_ITEM) * D, stream);
    hipMemsetAsync(cnt_ui, 0, sizeof(float) * (size_t)(N_ITEM + N_USER), stream);

    gather_kernel<<<(N_USER * 32 + 255) / 256, 256, 0, stream>>>(user_emb, user_ids, x_user, N_USER);

    // user -> item
    scatter_kernel<<<(N_EDGE * 32 + 255) / 256, 256, 0, stream>>>(
        x_user, edge_ui, edge_ui + N_EDGE, out_item, cnt_ui, N_EDGE);
    // item -> user
    scatter_kernel<<<(N_EDGE * 32 + 255) / 256, 256, 0, stream>>>(
        item_x, edge_iu, edge_iu + N_EDGE, out_user, cnt_iu, N_EDGE);

    finish_kernel<<<(N_ITEM + BM - 1) / BM, 256, 0, stream>>>(
        out_item, item_x, W_l_ui, W_r_ui, b_ui, cnt_ui, N_ITEM);
    finish_kernel<<<(N_USER + BM - 1) / BM, 256, 0, stream>>>(
        out_user, x_user, W_l_iu, W_r_iu, b_iu, cnt_iu, N_USER);
}

// Round 2
// 632.789 us; speedup vs baseline: 4.5773x; 4.5773x over previous
//
#include <hip/hip_runtime.h>

#define N_USER 50000
#define N_ITEM 50000
#define N_EDGE 800000
#define D 128

// ---------------------------------------------------------------------------
// Gather rows: out[r] = emb[ids[r]]   (32 threads/row, float4 each)
// ---------------------------------------------------------------------------
__global__ void gather_kernel(const float* __restrict__ emb, const int* __restrict__ ids,
                              float* __restrict__ out, int nRows) {
    int gid = blockIdx.x * blockDim.x + threadIdx.x;
    int row = gid >> 5;
    if (row >= nRows) return;
    int c = (gid & 31) << 2;
    int src = ids[row];
    const float4 v = *reinterpret_cast<const float4*>(emb + (size_t)src * D + c);
    *reinterpret_cast<float4*>(out + (size_t)row * D + c) = v;
}

// ---------------------------------------------------------------------------
// CSR build: count -> scan(+cursor init) -> fill
// ---------------------------------------------------------------------------
__global__ void count_kernel(const int* __restrict__ edst, int* __restrict__ cnt, int nE) {
    int e = blockIdx.x * blockDim.x + threadIdx.x;
    if (e < nE) atomicAdd(&cnt[edst[e]], 1);
}

__global__ __launch_bounds__(1024) void scan_kernel(const int* __restrict__ cnt,
                                                    int* __restrict__ off,
                                                    int* __restrict__ cur, int n) {
    __shared__ int part[1024];
    const int tid = threadIdx.x;
    const int chunk = (n + 1023) / 1024;
    const int s = tid * chunk;
    const int e = min(s + chunk, n);
    int sum = 0;
    for (int i = s; i < e; ++i) sum += cnt[i];
    part[tid] = sum;
    __syncthreads();
    // inclusive Hillis-Steele scan over partials
    for (int d = 1; d < 1024; d <<= 1) {
        int v = (tid >= d) ? part[tid - d] : 0;
        __syncthreads();
        part[tid] += v;
        __syncthreads();
    }
    int run = (tid > 0) ? part[tid - 1] : 0;
    for (int i = s; i < e; ++i) {
        off[i] = run;
        cur[i] = run;
        run += cnt[i];
    }
    if (tid == 1023) off[n] = part[1023];
}

__global__ void fill_kernel(const int* __restrict__ esrc, const int* __restrict__ edst,
                            int* __restrict__ cur, int* __restrict__ csr, int nE) {
    int e = blockIdx.x * blockDim.x + threadIdx.x;
    if (e >= nE) return;
    int d = edst[e];
    int pos = atomicAdd(&cur[d], 1);
    csr[pos] = esrc[e];
}

// ---------------------------------------------------------------------------
// Aggregate (mean): one 64-lane wave per destination row, float2 per lane.
// Writes the mean directly (0 for isolated rows).
// ---------------------------------------------------------------------------
__global__ __launch_bounds__(256) void aggregate_kernel(
    const float* __restrict__ feat, const int* __restrict__ off,
    const int* __restrict__ csr, float* __restrict__ agg, int nRows)
{
    int r = (blockIdx.x * blockDim.x + threadIdx.x) >> 6;
    if (r >= nRows) return;
    const int lane = threadIdx.x & 63;
    const int o0 = off[r], o1 = off[r + 1];
    float ax = 0.f, ay = 0.f;
    const int co = lane * 2;
    int i = o0;
    for (; i + 3 < o1; i += 4) {
        int s0 = csr[i], s1 = csr[i + 1], s2 = csr[i + 2], s3 = csr[i + 3];
        float2 v0 = *reinterpret_cast<const float2*>(feat + (size_t)s0 * D + co);
        float2 v1 = *reinterpret_cast<const float2*>(feat + (size_t)s1 * D + co);
        float2 v2 = *reinterpret_cast<const float2*>(feat + (size_t)s2 * D + co);
        float2 v3 = *reinterpret_cast<const float2*>(feat + (size_t)s3 * D + co);
        ax += v0.x + v1.x + v2.x + v3.x;
        ay += v0.y + v1.y + v2.y + v3.y;
    }
    for (; i < o1; ++i) {
        int s = csr[i];
        float2 v = *reinterpret_cast<const float2*>(feat + (size_t)s * D + co);
        ax += v.x; ay += v.y;
    }
    int deg = o1 - o0;
    float sc = (deg > 0) ? 1.0f / (float)deg : 0.0f;
    float2 outv = make_float2(ax * sc, ay * sc);
    *reinterpret_cast<float2*>(agg + (size_t)r * D + co) = outv;
}

// ---------------------------------------------------------------------------
// Fused epilogue: out[m] = agg[m] @ Wl + x[m] @ Wr + b   (in-place on agg)
// M-tile 64, K=256 (128 agg + 128 x), KC=32; 256 thr, 8x4 acc each.
// ---------------------------------------------------------------------------
#define BM 64
#define KC 32
#define APAD 68

__global__ __launch_bounds__(256) void finish_kernel(
    float* __restrict__ agg_out, const float* __restrict__ xr,
    const float* __restrict__ Wl, const float* __restrict__ Wr,
    const float* __restrict__ bias, int nRows)
{
    __shared__ __align__(16) float At[KC][APAD];
    __shared__ __align__(16) float Wt[KC][D];

    const int tid = threadIdx.x;
    const int block_row = blockIdx.x * BM;
    const int tn = tid & 31;
    const int tm = tid >> 5;

    float acc[8][4];
#pragma unroll
    for (int i = 0; i < 8; ++i)
#pragma unroll
        for (int j = 0; j < 4; ++j) acc[i][j] = 0.f;

    for (int kc = 0; kc < 2 * D; kc += KC) {
        __syncthreads();
#pragma unroll
        for (int l = 0; l < 2; ++l) {
            int f = tid + l * 256;
            int m = f >> 3;
            int kq = (f & 7) << 2;
            int gr = block_row + m;
            float4 v = make_float4(0.f, 0.f, 0.f, 0.f);
            if (gr < nRows) {
                int k0 = kc + kq;
                if (k0 < D) {
                    v = *reinterpret_cast<const float4*>(agg_out + (size_t)gr * D + k0);
                } else {
                    v = *reinterpret_cast<const float4*>(xr + (size_t)gr * D + (k0 - D));
                }
            }
            At[kq + 0][m] = v.x;
            At[kq + 1][m] = v.y;
            At[kq + 2][m] = v.z;
            At[kq + 3][m] = v.w;
        }
        const float* Wsrc = (kc < D) ? (Wl + (size_t)kc * D) : (Wr + (size_t)(kc - D) * D);
#pragma unroll
        for (int l = 0; l < 4; ++l) {
            int f = tid + l * 256;
            int k = f >> 5;
            int n4 = (f & 31) << 2;
            float4 v = *reinterpret_cast<const float4*>(Wsrc + (size_t)k * D + n4);
            *reinterpret_cast<float4*>(&Wt[k][n4]) = v;
        }
        __syncthreads();
#pragma unroll
        for (int k = 0; k < KC; ++k) {
            const float4 a0 = *reinterpret_cast<const float4*>(&At[k][tm * 8]);
            const float4 a1 = *reinterpret_cast<const float4*>(&At[k][tm * 8 + 4]);
            const float4 wv = *reinterpret_cast<const float4*>(&Wt[k][tn * 4]);
            const float a[8] = {a0.x, a0.y, a0.z, a0.w, a1.x, a1.y, a1.z, a1.w};
            const float w[4] = {wv.x, wv.y, wv.z, wv.w};
#pragma unroll
            for (int i = 0; i < 8; ++i)
#pragma unroll
                for (int j = 0; j < 4; ++j) acc[i][j] += a[i] * w[j];
        }
    }

    float4 bv = *reinterpret_cast<const float4*>(bias + tn * 4);
#pragma unroll
    for (int i = 0; i < 8; ++i) {
        int r = block_row + tm * 8 + i;
        if (r < nRows) {
            float4 v = make_float4(acc[i][0] + bv.x, acc[i][1] + bv.y,
                                   acc[i][2] + bv.z, acc[i][3] + bv.w);
            *reinterpret_cast<float4*>(agg_out + (size_t)r * D + tn * 4) = v;
        }
    }
}

// ---------------------------------------------------------------------------
extern "C" void kernel_launch(void* const* d_in, const int* in_sizes, int n_in,
                              void* d_out, int out_size, void* d_ws, size_t ws_size,
                              hipStream_t stream) {
    const int*   user_ids = (const int*)d_in[0];
    const float* item_x   = (const float*)d_in[1];
    const int*   edge_ui  = (const int*)d_in[2];
    const int*   edge_iu  = (const int*)d_in[3];
    const float* user_emb = (const float*)d_in[4];
    const float* W_l_ui   = (const float*)d_in[5];
    const float* W_r_ui   = (const float*)d_in[6];
    const float* b_ui     = (const float*)d_in[7];
    const float* W_l_iu   = (const float*)d_in[8];
    const float* W_r_iu   = (const float*)d_in[9];
    const float* b_iu     = (const float*)d_in[10];

    float* out      = (float*)d_out;
    float* out_user = out;                        // user-side aggregation target
    float* out_item = out + (size_t)N_USER * D;   // item-side aggregation target

    // Workspace layout (CSR buffers reused across the two directions)
    float* x_user = (float*)d_ws;                         // N_USER*D floats
    int*   cnt    = (int*)(x_user + (size_t)N_USER * D);  // 50000
    int*   off    = cnt + 50000;                          // 50001
    int*   cur    = off + 50001;                          // 50000
    int*   csr    = cur + 50000;                          // N_EDGE

    const int EB = (N_EDGE + 255) / 256;

    gather_kernel<<<(N_USER * 32 + 255) / 256, 256, 0, stream>>>(user_emb, user_ids, x_user, N_USER);

    // ---- direction user -> item (dst = items) ----
    hipMemsetAsync(cnt, 0, 50000 * sizeof(int), stream);
    count_kernel<<<EB, 256, 0, stream>>>(edge_ui + N_EDGE, cnt, N_EDGE);
    scan_kernel<<<1, 1024, 0, stream>>>(cnt, off, cur, N_ITEM);
    fill_kernel<<<EB, 256, 0, stream>>>(edge_ui, edge_ui + N_EDGE, cur, csr, N_EDGE);
    aggregate_kernel<<<(N_ITEM * 64 + 255) / 256, 256, 0, stream>>>(x_user, off, csr, out_item, N_ITEM);
    finish_kernel<<<(N_ITEM + BM - 1) / BM, 256, 0, stream>>>(
        out_item, item_x, W_l_ui, W_r_ui, b_ui, N_ITEM);

    // ---- direction item -> user (dst = users) ----
    hipMemsetAsync(cnt, 0, 50000 * sizeof(int), stream);
    count_kernel<<<EB, 256, 0, stream>>>(edge_iu + N_EDGE, cnt, N_EDGE);
    scan_kernel<<<1, 1024, 0, stream>>>(cnt, off, cur, N_USER);
    fill_kernel<<<EB, 256, 0, stream>>>(edge_iu, edge_iu + N_EDGE, cur, csr, N_EDGE);
    aggregate_kernel<<<(N_USER * 64 + 255) / 256, 256, 0, stream>>>(item_x, off, csr, out_user, N_USER);
    finish_kernel<<<(N_USER + BM - 1) / BM, 256, 0, stream>>>(
        out_user, x_user, W_l_iu, W_r_iu, b_iu, N_USER);
}

// Round 3
// 428.686 us; speedup vs baseline: 6.7566x; 1.4761x over previous
//
#include <hip/hip_runtime.h>

#define N_USER 50000
#define N_ITEM 50000
#define N_EDGE 800000
#define D 128

// ---------------------------------------------------------------------------
// Gather rows: out[r] = emb[ids[r]]   (32 threads/row, float4 each)
// ---------------------------------------------------------------------------
__global__ void gather_kernel(const float* __restrict__ emb, const int* __restrict__ ids,
                              float* __restrict__ out, int nRows) {
    int gid = blockIdx.x * blockDim.x + threadIdx.x;
    int row = gid >> 5;
    if (row >= nRows) return;
    int c = (gid & 31) << 2;
    int src = ids[row];
    const float4 v = *reinterpret_cast<const float4*>(emb + (size_t)src * D + c);
    *reinterpret_cast<float4*>(out + (size_t)row * D + c) = v;
}

// ---------------------------------------------------------------------------
// CSR build: count -> hierarchical scan (partial/scan_bsum/finalize) -> fill
// ---------------------------------------------------------------------------
__global__ void count_kernel(const int* __restrict__ edst, int* __restrict__ cnt, int nE) {
    int e = blockIdx.x * blockDim.x + threadIdx.x;
    if (e < nE) atomicAdd(&cnt[edst[e]], 1);
}

#define SCAN_BLK 256

__global__ __launch_bounds__(SCAN_BLK) void partial_kernel(
    const int* __restrict__ cnt, int* __restrict__ bsum, int n) {
    __shared__ int s[SCAN_BLK];
    int tid = threadIdx.x;
    int i = blockIdx.x * SCAN_BLK + tid;
    s[tid] = (i < n) ? cnt[i] : 0;
    __syncthreads();
    for (int d = SCAN_BLK / 2; d > 0; d >>= 1) {
        if (tid < d) s[tid] += s[tid + d];
        __syncthreads();
    }
    if (tid == 0) bsum[blockIdx.x] = s[0];
}

// single block; nb <= 256
__global__ __launch_bounds__(256) void scan_bsum_kernel(int* __restrict__ bsum, int nb) {
    __shared__ int s[256];
    int tid = threadIdx.x;
    int v = (tid < nb) ? bsum[tid] : 0;
    s[tid] = v;
    __syncthreads();
    for (int d = 1; d < 256; d <<= 1) {
        int t = (tid >= d) ? s[tid - d] : 0;
        __syncthreads();
        s[tid] += t;
        __syncthreads();
    }
    if (tid < nb) bsum[tid] = s[tid] - v;  // exclusive prefix of block sums
}

__global__ __launch_bounds__(SCAN_BLK) void finalize_kernel(
    const int* __restrict__ cnt, const int* __restrict__ bsum,
    int* __restrict__ off, int* __restrict__ cur, int n) {
    __shared__ int s[SCAN_BLK];
    int tid = threadIdx.x;
    int i = blockIdx.x * SCAN_BLK + tid;
    int v = (i < n) ? cnt[i] : 0;
    s[tid] = v;
    __syncthreads();
    for (int d = 1; d < SCAN_BLK; d <<= 1) {
        int t = (tid >= d) ? s[tid - d] : 0;
        __syncthreads();
        s[tid] += t;
        __syncthreads();
    }
    int incl = s[tid] + bsum[blockIdx.x];
    int excl = incl - v;
    if (i < n) {
        off[i] = excl;
        cur[i] = excl;
        if (i == n - 1) off[n] = incl;
    }
}

__global__ void fill_kernel(const int* __restrict__ esrc, const int* __restrict__ edst,
                            int* __restrict__ cur, int* __restrict__ csr, int nE) {
    int e = blockIdx.x * blockDim.x + threadIdx.x;
    if (e >= nE) return;
    int d = edst[e];
    int pos = atomicAdd(&cur[d], 1);
    csr[pos] = esrc[e];
}

// ---------------------------------------------------------------------------
// Aggregate (mean): one 64-lane wave per destination row, float2 per lane.
// ---------------------------------------------------------------------------
__global__ __launch_bounds__(256) void aggregate_kernel(
    const float* __restrict__ feat, const int* __restrict__ off,
    const int* __restrict__ csr, float* __restrict__ agg, int nRows)
{
    int r = (blockIdx.x * blockDim.x + threadIdx.x) >> 6;
    if (r >= nRows) return;
    const int lane = threadIdx.x & 63;
    const int o0 = off[r], o1 = off[r + 1];
    float ax = 0.f, ay = 0.f;
    const int co = lane * 2;
    int i = o0;
    for (; i + 3 < o1; i += 4) {
        int s0 = csr[i], s1 = csr[i + 1], s2 = csr[i + 2], s3 = csr[i + 3];
        float2 v0 = *reinterpret_cast<const float2*>(feat + (size_t)s0 * D + co);
        float2 v1 = *reinterpret_cast<const float2*>(feat + (size_t)s1 * D + co);
        float2 v2 = *reinterpret_cast<const float2*>(feat + (size_t)s2 * D + co);
        float2 v3 = *reinterpret_cast<const float2*>(feat + (size_t)s3 * D + co);
        ax += v0.x + v1.x + v2.x + v3.x;
        ay += v0.y + v1.y + v2.y + v3.y;
    }
    for (; i < o1; ++i) {
        int s = csr[i];
        float2 v = *reinterpret_cast<const float2*>(feat + (size_t)s * D + co);
        ax += v.x; ay += v.y;
    }
    int deg = o1 - o0;
    float sc = (deg > 0) ? 1.0f / (float)deg : 0.0f;
    float2 outv = make_float2(ax * sc, ay * sc);
    *reinterpret_cast<float2*>(agg + (size_t)r * D + co) = outv;
}

// ---------------------------------------------------------------------------
// Fused epilogue: out[m] = agg[m] @ Wl + x[m] @ Wr + b   (in-place on agg)
// M-tile 64, K=256 (128 agg + 128 x), KC=32; 256 thr, 8x4 acc each.
// ---------------------------------------------------------------------------
#define BM 64
#define KC 32
#define APAD 68

__global__ __launch_bounds__(256) void finish_kernel(
    float* __restrict__ agg_out, const float* __restrict__ xr,
    const float* __restrict__ Wl, const float* __restrict__ Wr,
    const float* __restrict__ bias, int nRows)
{
    __shared__ __align__(16) float At[KC][APAD];
    __shared__ __align__(16) float Wt[KC][D];

    const int tid = threadIdx.x;
    const int block_row = blockIdx.x * BM;
    const int tn = tid & 31;
    const int tm = tid >> 5;

    float acc[8][4];
#pragma unroll
    for (int i = 0; i < 8; ++i)
#pragma unroll
        for (int j = 0; j < 4; ++j) acc[i][j] = 0.f;

    for (int kc = 0; kc < 2 * D; kc += KC) {
        __syncthreads();
#pragma unroll
        for (int l = 0; l < 2; ++l) {
            int f = tid + l * 256;
            int m = f >> 3;
            int kq = (f & 7) << 2;
            int gr = block_row + m;
            float4 v = make_float4(0.f, 0.f, 0.f, 0.f);
            if (gr < nRows) {
                int k0 = kc + kq;
                if (k0 < D) {
                    v = *reinterpret_cast<const float4*>(agg_out + (size_t)gr * D + k0);
                } else {
                    v = *reinterpret_cast<const float4*>(xr + (size_t)gr * D + (k0 - D));
                }
            }
            At[kq + 0][m] = v.x;
            At[kq + 1][m] = v.y;
            At[kq + 2][m] = v.z;
            At[kq + 3][m] = v.w;
        }
        const float* Wsrc = (kc < D) ? (Wl + (size_t)kc * D) : (Wr + (size_t)(kc - D) * D);
#pragma unroll
        for (int l = 0; l < 4; ++l) {
            int f = tid + l * 256;
            int k = f >> 5;
            int n4 = (f & 31) << 2;
            float4 v = *reinterpret_cast<const float4*>(Wsrc + (size_t)k * D + n4);
            *reinterpret_cast<float4*>(&Wt[k][n4]) = v;
        }
        __syncthreads();
#pragma unroll
        for (int k = 0; k < KC; ++k) {
            const float4 a0 = *reinterpret_cast<const float4*>(&At[k][tm * 8]);
            const float4 a1 = *reinterpret_cast<const float4*>(&At[k][tm * 8 + 4]);
            const float4 wv = *reinterpret_cast<const float4*>(&Wt[k][tn * 4]);
            const float a[8] = {a0.x, a0.y, a0.z, a0.w, a1.x, a1.y, a1.z, a1.w};
            const float w[4] = {wv.x, wv.y, wv.z, wv.w};
#pragma unroll
            for (int i = 0; i < 8; ++i)
#pragma unroll
                for (int j = 0; j < 4; ++j) acc[i][j] += a[i] * w[j];
        }
    }

    float4 bv = *reinterpret_cast<const float4*>(bias + tn * 4);
#pragma unroll
    for (int i = 0; i < 8; ++i) {
        int r = block_row + tm * 8 + i;
        if (r < nRows) {
            float4 v = make_float4(acc[i][0] + bv.x, acc[i][1] + bv.y,
                                   acc[i][2] + bv.z, acc[i][3] + bv.w);
            *reinterpret_cast<float4*>(agg_out + (size_t)r * D + tn * 4) = v;
        }
    }
}

// ---------------------------------------------------------------------------
extern "C" void kernel_launch(void* const* d_in, const int* in_sizes, int n_in,
                              void* d_out, int out_size, void* d_ws, size_t ws_size,
                              hipStream_t stream) {
    const int*   user_ids = (const int*)d_in[0];
    const float* item_x   = (const float*)d_in[1];
    const int*   edge_ui  = (const int*)d_in[2];
    const int*   edge_iu  = (const int*)d_in[3];
    const float* user_emb = (const float*)d_in[4];
    const float* W_l_ui   = (const float*)d_in[5];
    const float* W_r_ui   = (const float*)d_in[6];
    const float* b_ui     = (const float*)d_in[7];
    const float* W_l_iu   = (const float*)d_in[8];
    const float* W_r_iu   = (const float*)d_in[9];
    const float* b_iu     = (const float*)d_in[10];

    float* out      = (float*)d_out;
    float* out_user = out;                        // user-side aggregation target
    float* out_item = out + (size_t)N_USER * D;   // item-side aggregation target

    // Workspace layout (CSR buffers reused across the two directions)
    float* x_user = (float*)d_ws;                         // N_USER*D floats
    int*   cnt    = (int*)(x_user + (size_t)N_USER * D);  // 50000
    int*   off    = cnt + 50000;                          // 50001
    int*   cur    = off + 50001;                          // 50000
    int*   csr    = cur + 50000;                          // N_EDGE
    int*   bsum   = csr + N_EDGE;                         // <= 256

    const int EB = (N_EDGE + 255) / 256;
    const int NB_U = (N_USER + SCAN_BLK - 1) / SCAN_BLK;  // 196
    const int NB_I = (N_ITEM + SCAN_BLK - 1) / SCAN_BLK;  // 196

    gather_kernel<<<(N_USER * 32 + 255) / 256, 256, 0, stream>>>(user_emb, user_ids, x_user, N_USER);

    // ---- direction user -> item (dst = items) ----
    hipMemsetAsync(cnt, 0, 50000 * sizeof(int), stream);
    count_kernel<<<EB, 256, 0, stream>>>(edge_ui + N_EDGE, cnt, N_EDGE);
    partial_kernel<<<NB_I, SCAN_BLK, 0, stream>>>(cnt, bsum, N_ITEM);
    scan_bsum_kernel<<<1, 256, 0, stream>>>(bsum, NB_I);
    finalize_kernel<<<NB_I, SCAN_BLK, 0, stream>>>(cnt, bsum, off, cur, N_ITEM);
    fill_kernel<<<EB, 256, 0, stream>>>(edge_ui, edge_ui + N_EDGE, cur, csr, N_EDGE);
    aggregate_kernel<<<(N_ITEM * 64 + 255) / 256, 256, 0, stream>>>(x_user, off, csr, out_item, N_ITEM);
    finish_kernel<<<(N_ITEM + BM - 1) / BM, 256, 0, stream>>>(
        out_item, item_x, W_l_ui, W_r_ui, b_ui, N_ITEM);

    // ---- direction item -> user (dst = users) ----
    hipMemsetAsync(cnt, 0, 50000 * sizeof(int), stream);
    count_kernel<<<EB, 256, 0, stream>>>(edge_iu + N_EDGE, cnt, N_EDGE);
    partial_kernel<<<NB_U, SCAN_BLK, 0, stream>>>(cnt, bsum, N_USER);
    scan_bsum_kernel<<<1, 256, 0, stream>>>(bsum, NB_U);
    finalize_kernel<<<NB_U, SCAN_BLK, 0, stream>>>(cnt, bsum, off, cur, N_USER);
    fill_kernel<<<EB, 256, 0, stream>>>(edge_iu, edge_iu + N_EDGE, cur, csr, N_EDGE);
    aggregate_kernel<<<(N_USER * 64 + 255) / 256, 256, 0, stream>>>(item_x, off, csr, out_user, N_USER);
    finish_kernel<<<(N_USER + BM - 1) / BM, 256, 0, stream>>>(
        out_user, x_user, W_l_iu, W_r_iu, b_iu, N_USER);
}

// Round 4
// 334.527 us; speedup vs baseline: 8.6584x; 1.2815x over previous
//
#include <hip/hip_runtime.h>

#define N_USER 50000
#define N_ITEM 50000
#define N_EDGE 800000
#define D 128

typedef __attribute__((ext_vector_type(8))) short     bf16x8;
typedef __attribute__((ext_vector_type(4))) float     f32x4;
typedef __attribute__((ext_vector_type(4))) unsigned short ushortx4;
typedef __attribute__((ext_vector_type(8))) unsigned short ushortx8;

__device__ __forceinline__ unsigned short f2bf(float f) {
    unsigned int u = __float_as_uint(f);
    unsigned int r = (u + 0x7fffu + ((u >> 16) & 1u)) >> 16;   // RNE
    return (unsigned short)r;
}
__device__ __forceinline__ float bf2f(unsigned short b) {
    return __uint_as_float(((unsigned int)b) << 16);
}

// ---------------------------------------------------------------------------
// Pack target features (optionally gathered by ids) into the bf16 tail half
// of A: Atail[row*256 + c] = bf16(src[(ids?ids[row]:row)*128 + c])
// 32 lanes/row, 4 floats each -> 8B bf16 store.
// ---------------------------------------------------------------------------
__global__ void packA_kernel(const float* __restrict__ src, const int* __restrict__ ids,
                             unsigned short* __restrict__ Atail, int nRows) {
    int gid = blockIdx.x * blockDim.x + threadIdx.x;
    int row = gid >> 5;
    if (row >= nRows) return;
    int c = (gid & 31) << 2;
    int s = ids ? ids[row] : row;
    const float4 v = *reinterpret_cast<const float4*>(src + (size_t)s * D + c);
    ushortx4 o;
    o.x = f2bf(v.x); o.y = f2bf(v.y); o.z = f2bf(v.z); o.w = f2bf(v.w);
    *reinterpret_cast<ushortx4*>(Atail + (size_t)row * 256 + c) = o;
}

// ---------------------------------------------------------------------------
// Pack W (fp32 [128][128] x2 stacked as K=256) into MFMA B-fragment layout:
// Wfrag[((ks*8 + c)*64 + lane)*8 + i] = bf16(B[k][col]),
//   k = ks*32 + (lane>>4)*8 + i,  col = c*16 + (lane&15)
// ---------------------------------------------------------------------------
__global__ void packW_kernel(const float* __restrict__ Wl, const float* __restrict__ Wr,
                             unsigned short* __restrict__ Wfrag) {
    int id = blockIdx.x * blockDim.x + threadIdx.x;   // [0, 4096)
    if (id >= 4096) return;
    int lane = id & 63;
    int c    = (id >> 6) & 7;
    int ks   = id >> 9;
    int col  = c * 16 + (lane & 15);
    int k0   = ks * 32 + (lane >> 4) * 8;
    ushortx8 o;
#pragma unroll
    for (int i = 0; i < 8; ++i) {
        int k = k0 + i;
        float f = (k < D) ? Wl[(size_t)k * D + col] : Wr[(size_t)(k - D) * D + col];
        o[i] = f2bf(f);
    }
    *reinterpret_cast<ushortx8*>(Wfrag + (size_t)id * 8) = o;
}

// ---------------------------------------------------------------------------
// CSR build: count -> hierarchical scan -> fill
// ---------------------------------------------------------------------------
__global__ void count_kernel(const int* __restrict__ edst, int* __restrict__ cnt, int nE) {
    int e = blockIdx.x * blockDim.x + threadIdx.x;
    if (e < nE) atomicAdd(&cnt[edst[e]], 1);
}

#define SCAN_BLK 256

__global__ __launch_bounds__(SCAN_BLK) void partial_kernel(
    const int* __restrict__ cnt, int* __restrict__ bsum, int n) {
    __shared__ int s[SCAN_BLK];
    int tid = threadIdx.x;
    int i = blockIdx.x * SCAN_BLK + tid;
    s[tid] = (i < n) ? cnt[i] : 0;
    __syncthreads();
    for (int d = SCAN_BLK / 2; d > 0; d >>= 1) {
        if (tid < d) s[tid] += s[tid + d];
        __syncthreads();
    }
    if (tid == 0) bsum[blockIdx.x] = s[0];
}

__global__ __launch_bounds__(256) void scan_bsum_kernel(int* __restrict__ bsum, int nb) {
    __shared__ int s[256];
    int tid = threadIdx.x;
    int v = (tid < nb) ? bsum[tid] : 0;
    s[tid] = v;
    __syncthreads();
    for (int d = 1; d < 256; d <<= 1) {
        int t = (tid >= d) ? s[tid - d] : 0;
        __syncthreads();
        s[tid] += t;
        __syncthreads();
    }
    if (tid < nb) bsum[tid] = s[tid] - v;  // exclusive prefix of block sums
}

__global__ __launch_bounds__(SCAN_BLK) void finalize_kernel(
    const int* __restrict__ cnt, const int* __restrict__ bsum,
    int* __restrict__ off, int* __restrict__ cur, int n) {
    __shared__ int s[SCAN_BLK];
    int tid = threadIdx.x;
    int i = blockIdx.x * SCAN_BLK + tid;
    int v = (i < n) ? cnt[i] : 0;
    s[tid] = v;
    __syncthreads();
    for (int d = 1; d < SCAN_BLK; d <<= 1) {
        int t = (tid >= d) ? s[tid - d] : 0;
        __syncthreads();
        s[tid] += t;
        __syncthreads();
    }
    int incl = s[tid] + bsum[blockIdx.x];
    int excl = incl - v;
    if (i < n) {
        off[i] = excl;
        cur[i] = excl;
        if (i == n - 1) off[n] = incl;
    }
}

__global__ void fill_kernel(const int* __restrict__ esrc, const int* __restrict__ edst,
                            int* __restrict__ cur, int* __restrict__ csr, int nE) {
    int e = blockIdx.x * blockDim.x + threadIdx.x;
    if (e >= nE) return;
    int d = edst[e];
    int pos = atomicAdd(&cur[d], 1);
    csr[pos] = esrc[e];
}

// ---------------------------------------------------------------------------
// Aggregate (mean) in bf16: one 64-lane wave per destination row.
// feat: bf16 rows with stride 256 elements (source table = tail half of the
// other A matrix). aggout: bf16 head half of this A matrix (stride 256).
// Lane handles 2 dims (one uint = 2 bf16).
// ---------------------------------------------------------------------------
__global__ __launch_bounds__(256) void aggregate_kernel(
    const unsigned short* __restrict__ feat, const int* __restrict__ off,
    const int* __restrict__ csr, unsigned short* __restrict__ aggout, int nRows)
{
    int r = (blockIdx.x * blockDim.x + threadIdx.x) >> 6;
    if (r >= nRows) return;
    const int lane = threadIdx.x & 63;
    const int o0 = off[r], o1 = off[r + 1];
    const int co = lane * 2;
    float ax = 0.f, ay = 0.f;
    int i = o0;
    for (; i + 3 < o1; i += 4) {
        int s0 = csr[i], s1 = csr[i + 1], s2 = csr[i + 2], s3 = csr[i + 3];
        unsigned int w0 = *reinterpret_cast<const unsigned int*>(feat + (size_t)s0 * 256 + co);
        unsigned int w1 = *reinterpret_cast<const unsigned int*>(feat + (size_t)s1 * 256 + co);
        unsigned int w2 = *reinterpret_cast<const unsigned int*>(feat + (size_t)s2 * 256 + co);
        unsigned int w3 = *reinterpret_cast<const unsigned int*>(feat + (size_t)s3 * 256 + co);
        ax += bf2f((unsigned short)w0) + bf2f((unsigned short)w1)
            + bf2f((unsigned short)w2) + bf2f((unsigned short)w3);
        ay += bf2f((unsigned short)(w0 >> 16)) + bf2f((unsigned short)(w1 >> 16))
            + bf2f((unsigned short)(w2 >> 16)) + bf2f((unsigned short)(w3 >> 16));
    }
    for (; i < o1; ++i) {
        int s = csr[i];
        unsigned int w = *reinterpret_cast<const unsigned int*>(feat + (size_t)s * 256 + co);
        ax += bf2f((unsigned short)w);
        ay += bf2f((unsigned short)(w >> 16));
    }
    int deg = o1 - o0;
    float sc = (deg > 0) ? 1.0f / (float)deg : 0.0f;
    unsigned int outw = (unsigned int)f2bf(ax * sc) | ((unsigned int)f2bf(ay * sc) << 16);
    *reinterpret_cast<unsigned int*>(aggout + (size_t)r * 256 + co) = outw;
}

// ---------------------------------------------------------------------------
// MFMA finish: out[M][128] = A[M][256]bf16 @ Wfrag + bias, IN-PLACE over A
// (out and A alias byte-for-byte per row: 256*2B == 128*4B; safe because each
// wave's stores depend on all of its loads and waves own disjoint rows).
// Block: 256 thr = 4 waves; wave w computes rows [blk*64+16w, +16), all 128 cols.
// ---------------------------------------------------------------------------
__global__ __launch_bounds__(256) void finish_mfma_kernel(
    const unsigned short* A, const unsigned short* __restrict__ Wfrag,
    const float* __restrict__ bias, float* outp, int M)
{
    const int tid  = threadIdx.x;
    const int wave = tid >> 6;
    const int lane = tid & 63;
    const int kg   = lane >> 4;                    // 0..3
    const int rowBase = blockIdx.x * 64 + wave * 16;

    int arow = rowBase + (lane & 15);
    int arow_c = (arow < M) ? arow : (M - 1);
    const unsigned short* arow_ptr = A + (size_t)arow_c * 256 + kg * 8;

    f32x4 acc[8];
#pragma unroll
    for (int c = 0; c < 8; ++c) acc[c] = (f32x4){0.f, 0.f, 0.f, 0.f};

#pragma unroll
    for (int ks = 0; ks < 8; ++ks) {
        bf16x8 a = *reinterpret_cast<const bf16x8*>(arow_ptr + ks * 32);
        const unsigned short* bptr = Wfrag + ((size_t)(ks * 8) * 64 + lane) * 8;
#pragma unroll
        for (int c = 0; c < 8; ++c) {
            bf16x8 b = *reinterpret_cast<const bf16x8*>(bptr + (size_t)c * 512);
            acc[c] = __builtin_amdgcn_mfma_f32_16x16x32_bf16(a, b, acc[c], 0, 0, 0);
        }
    }

    const int orow0 = rowBase + kg * 4;
    const int ocol  = lane & 15;
#pragma unroll
    for (int c = 0; c < 8; ++c) {
        float bv = bias[c * 16 + ocol];
#pragma unroll
        for (int r = 0; r < 4; ++r) {
            int row = orow0 + r;
            if (row < M) outp[(size_t)row * 128 + c * 16 + ocol] = acc[c][r] + bv;
        }
    }
}

// ---------------------------------------------------------------------------
extern "C" void kernel_launch(void* const* d_in, const int* in_sizes, int n_in,
                              void* d_out, int out_size, void* d_ws, size_t ws_size,
                              hipStream_t stream) {
    const int*   user_ids = (const int*)d_in[0];
    const float* item_x   = (const float*)d_in[1];
    const int*   edge_ui  = (const int*)d_in[2];
    const int*   edge_iu  = (const int*)d_in[3];
    const float* user_emb = (const float*)d_in[4];
    const float* W_l_ui   = (const float*)d_in[5];
    const float* W_r_ui   = (const float*)d_in[6];
    const float* b_ui     = (const float*)d_in[7];
    const float* W_l_iu   = (const float*)d_in[8];
    const float* W_r_iu   = (const float*)d_in[9];
    const float* b_iu     = (const float*)d_in[10];

    // A matrices live inside d_out: bf16 [50000][256] == fp32 [50000][128] bytes.
    unsigned short* A_user = (unsigned short*)d_out;                  // -> out_user
    unsigned short* A_item = A_user + (size_t)N_USER * 256;           // -> out_item
    float* out_user = (float*)d_out;
    float* out_item = out_user + (size_t)N_USER * D;

    // Workspace (16B-aligned blocks first)
    unsigned short* WfragUI = (unsigned short*)d_ws;      // 32768 ushorts (64KB)
    unsigned short* WfragIU = WfragUI + 32768;            // 32768
    int* cnt  = (int*)(WfragIU + 32768);                  // 50000
    int* off  = cnt + 50000;                              // 50001
    int* cur  = off + 50001;                              // 50000
    int* csr  = cur + 50000;                              // N_EDGE
    int* bsum = csr + N_EDGE;                             // <= 256

    const int EB   = (N_EDGE + 255) / 256;
    const int NB_U = (N_USER + SCAN_BLK - 1) / SCAN_BLK;
    const int NB_I = (N_ITEM + SCAN_BLK - 1) / SCAN_BLK;

    // --- pack phase ---
    packA_kernel<<<(N_USER * 32 + 255) / 256, 256, 0, stream>>>(
        user_emb, user_ids, A_user + 128, N_USER);                 // user features -> A_user tail
    packA_kernel<<<(N_ITEM * 32 + 255) / 256, 256, 0, stream>>>(
        item_x, nullptr, A_item + 128, N_ITEM);                    // item features -> A_item tail
    packW_kernel<<<16, 256, 0, stream>>>(W_l_ui, W_r_ui, WfragUI);
    packW_kernel<<<16, 256, 0, stream>>>(W_l_iu, W_r_iu, WfragIU);

    // --- direction user -> item (dst = items): agg over user features ---
    hipMemsetAsync(cnt, 0, 50000 * sizeof(int), stream);
    count_kernel<<<EB, 256, 0, stream>>>(edge_ui + N_EDGE, cnt, N_EDGE);
    partial_kernel<<<NB_I, SCAN_BLK, 0, stream>>>(cnt, bsum, N_ITEM);
    scan_bsum_kernel<<<1, 256, 0, stream>>>(bsum, NB_I);
    finalize_kernel<<<NB_I, SCAN_BLK, 0, stream>>>(cnt, bsum, off, cur, N_ITEM);
    fill_kernel<<<EB, 256, 0, stream>>>(edge_ui, edge_ui + N_EDGE, cur, csr, N_EDGE);
    aggregate_kernel<<<(N_ITEM * 64 + 255) / 256, 256, 0, stream>>>(
        A_user + 128, off, csr, A_item, N_ITEM);

    // --- direction item -> user (dst = users): agg over item features ---
    hipMemsetAsync(cnt, 0, 50000 * sizeof(int), stream);
    count_kernel<<<EB, 256, 0, stream>>>(edge_iu + N_EDGE, cnt, N_EDGE);
    partial_kernel<<<NB_U, SCAN_BLK, 0, stream>>>(cnt, bsum, N_USER);
    scan_bsum_kernel<<<1, 256, 0, stream>>>(bsum, NB_U);
    finalize_kernel<<<NB_U, SCAN_BLK, 0, stream>>>(cnt, bsum, off, cur, N_USER);
    fill_kernel<<<EB, 256, 0, stream>>>(edge_iu, edge_iu + N_EDGE, cur, csr, N_EDGE);
    aggregate_kernel<<<(N_USER * 64 + 255) / 256, 256, 0, stream>>>(
        A_item + 128, off, csr, A_user, N_USER);

    // --- MFMA epilogues (in-place over their A) ---
    // NOTE: finish(A_item) must come AFTER aggregate over A_item tail (it does).
    finish_mfma_kernel<<<(N_ITEM + 63) / 64, 256, 0, stream>>>(
        A_item, WfragUI, b_ui, out_item, N_ITEM);
    finish_mfma_kernel<<<(N_USER + 63) / 64, 256, 0, stream>>>(
        A_user, WfragIU, b_iu, out_user, N_USER);
}

// Round 5
// 292.008 us; speedup vs baseline: 9.9191x; 1.1456x over previous
//
#include <hip/hip_runtime.h>

#define N_USER 50000
#define N_ITEM 50000
#define N_EDGE 800000
#define D 128
#define NTOT   100000          // combined dst space: [0,50K)=items, [50K,100K)=users
#define NE2    1600000         // both directions' edges

typedef __attribute__((ext_vector_type(8))) short     bf16x8;
typedef __attribute__((ext_vector_type(4))) float     f32x4;
typedef __attribute__((ext_vector_type(4))) unsigned short ushortx4;
typedef __attribute__((ext_vector_type(8))) unsigned short ushortx8;

__device__ __forceinline__ unsigned short f2bf(float f) {
    unsigned int u = __float_as_uint(f);
    unsigned int r = (u + 0x7fffu + ((u >> 16) & 1u)) >> 16;   // RNE
    return (unsigned short)r;
}
__device__ __forceinline__ float bf2f(unsigned short b) {
    return __uint_as_float(((unsigned int)b) << 16);
}

// ---------------------------------------------------------------------------
// PREP mega-kernel (block-range roles):
//  [0, 12500)        pack A tails: 100K rows x 32 lanes, fp32->bf16
//  [12500, 18750)    count: 1.6M edges -> cnt[NTOT] atomics
//  [18750, 18782)    pack W frags (2 x 4096 ids)
// ---------------------------------------------------------------------------
#define PACKA_BLOCKS 12500
#define COUNT_BLOCKS 6250
#define PACKW_BLOCKS 32

__global__ __launch_bounds__(256) void prep_kernel(
    const float* __restrict__ user_emb, const int* __restrict__ user_ids,
    const float* __restrict__ item_x,
    const int* __restrict__ edge_ui, const int* __restrict__ edge_iu,
    const float* __restrict__ Wl_ui, const float* __restrict__ Wr_ui,
    const float* __restrict__ Wl_iu, const float* __restrict__ Wr_iu,
    unsigned short* A_user, unsigned short* A_item,
    int* cnt, unsigned short* WfragUI, unsigned short* WfragIU)
{
    const int b = blockIdx.x;
    if (b < PACKA_BLOCKS) {
        int gid = b * 256 + threadIdx.x;
        int row = gid >> 5;
        int c = (gid & 31) << 2;
        const float* src;
        unsigned short* dst;
        if (row < N_USER) {
            src = user_emb + (size_t)user_ids[row] * D;
            dst = A_user + (size_t)row * 256 + 128;     // tail half
        } else {
            int r = row - N_USER;
            src = item_x + (size_t)r * D;
            dst = A_item + (size_t)r * 256 + 128;
        }
        const float4 v = *reinterpret_cast<const float4*>(src + c);
        ushortx4 o;
        o.x = f2bf(v.x); o.y = f2bf(v.y); o.z = f2bf(v.z); o.w = f2bf(v.w);
        *reinterpret_cast<ushortx4*>(dst + c) = o;
    } else if (b < PACKA_BLOCKS + COUNT_BLOCKS) {
        int e = (b - PACKA_BLOCKS) * 256 + threadIdx.x;   // [0, NE2)
        int d;
        if (e < N_EDGE) d = edge_ui[N_EDGE + e];                       // item dst
        else            d = N_ITEM + edge_iu[N_EDGE + (e - N_EDGE)];   // user dst
        atomicAdd(&cnt[d], 1);
    } else {
        int id = (b - PACKA_BLOCKS - COUNT_BLOCKS) * 256 + threadIdx.x; // [0,8192)
        const float *Wl, *Wr;
        unsigned short* Wf;
        if (id < 4096) { Wl = Wl_ui; Wr = Wr_ui; Wf = WfragUI; }
        else { id -= 4096; Wl = Wl_iu; Wr = Wr_iu; Wf = WfragIU; }
        int lane = id & 63;
        int c    = (id >> 6) & 7;
        int ks   = id >> 9;
        int col  = c * 16 + (lane & 15);
        int k0   = ks * 32 + (lane >> 4) * 8;
        ushortx8 o;
#pragma unroll
        for (int i = 0; i < 8; ++i) {
            int k = k0 + i;
            float f = (k < D) ? Wl[(size_t)k * D + col] : Wr[(size_t)(k - D) * D + col];
            o[i] = f2bf(f);
        }
        *reinterpret_cast<ushortx8*>(Wf + (size_t)id * 8) = o;
    }
}

// ---------------------------------------------------------------------------
// Hierarchical scan over combined cnt[NTOT]
// ---------------------------------------------------------------------------
#define SCAN_BLK 512

__global__ __launch_bounds__(SCAN_BLK) void partial_kernel(
    const int* __restrict__ cnt, int* __restrict__ bsum, int n) {
    __shared__ int s[SCAN_BLK];
    int tid = threadIdx.x;
    int i = blockIdx.x * SCAN_BLK + tid;
    s[tid] = (i < n) ? cnt[i] : 0;
    __syncthreads();
    for (int d = SCAN_BLK / 2; d > 0; d >>= 1) {
        if (tid < d) s[tid] += s[tid + d];
        __syncthreads();
    }
    if (tid == 0) bsum[blockIdx.x] = s[0];
}

__global__ __launch_bounds__(256) void scan_bsum_kernel(int* __restrict__ bsum, int nb) {
    __shared__ int s[256];
    int tid = threadIdx.x;
    int v = (tid < nb) ? bsum[tid] : 0;
    s[tid] = v;
    __syncthreads();
    for (int d = 1; d < 256; d <<= 1) {
        int t = (tid >= d) ? s[tid - d] : 0;
        __syncthreads();
        s[tid] += t;
        __syncthreads();
    }
    if (tid < nb) bsum[tid] = s[tid] - v;  // exclusive prefix of block sums
}

__global__ __launch_bounds__(SCAN_BLK) void finalize_kernel(
    const int* __restrict__ cnt, const int* __restrict__ bsum,
    int* __restrict__ off, int* __restrict__ cur, int n) {
    __shared__ int s[SCAN_BLK];
    int tid = threadIdx.x;
    int i = blockIdx.x * SCAN_BLK + tid;
    int v = (i < n) ? cnt[i] : 0;
    s[tid] = v;
    __syncthreads();
    for (int d = 1; d < SCAN_BLK; d <<= 1) {
        int t = (tid >= d) ? s[tid - d] : 0;
        __syncthreads();
        s[tid] += t;
        __syncthreads();
    }
    int incl = s[tid] + bsum[blockIdx.x];
    int excl = incl - v;
    if (i < n) {
        off[i] = excl;
        cur[i] = excl;
        if (i == n - 1) off[n] = incl;
    }
}

// ---------------------------------------------------------------------------
// Fill both directions into one uint16 CSR (src ids < 50000 fit in 16 bits)
// ---------------------------------------------------------------------------
__global__ void fill2_kernel(const int* __restrict__ edge_ui, const int* __restrict__ edge_iu,
                             int* __restrict__ cur, unsigned short* __restrict__ csr) {
    int e = blockIdx.x * blockDim.x + threadIdx.x;   // [0, NE2)
    int s, d;
    if (e < N_EDGE) {
        s = edge_ui[e];
        d = edge_ui[N_EDGE + e];
    } else {
        int f = e - N_EDGE;
        s = edge_iu[f];
        d = N_ITEM + edge_iu[N_EDGE + f];
    }
    int pos = atomicAdd(&cur[d], 1);
    csr[pos] = (unsigned short)s;
}

// ---------------------------------------------------------------------------
// Aggregate (mean) both directions: one 64-lane wave per combined dst row.
// r < 50K: item dst, feat = A_user tail, out = A_item head row r
// r >= 50K: user dst, feat = A_item tail, out = A_user head row r-50K
// ---------------------------------------------------------------------------
__global__ __launch_bounds__(256) void agg2_kernel(
    unsigned short* A_user, unsigned short* A_item,
    const int* __restrict__ off, const unsigned short* __restrict__ csr)
{
    int r = (blockIdx.x * blockDim.x + threadIdx.x) >> 6;
    if (r >= NTOT) return;
    const int lane = threadIdx.x & 63;
    const unsigned short* feat;
    unsigned short* outp;
    if (r < N_ITEM) { feat = A_user + 128; outp = A_item + (size_t)r * 256; }
    else            { feat = A_item + 128; outp = A_user + (size_t)(r - N_ITEM) * 256; }

    const int o0 = off[r], o1 = off[r + 1];
    const int co = lane * 2;
    float ax = 0.f, ay = 0.f;
    int i = o0;
    for (; i + 3 < o1; i += 4) {
        int s0 = csr[i], s1 = csr[i + 1], s2 = csr[i + 2], s3 = csr[i + 3];
        unsigned int w0 = *reinterpret_cast<const unsigned int*>(feat + (size_t)s0 * 256 + co);
        unsigned int w1 = *reinterpret_cast<const unsigned int*>(feat + (size_t)s1 * 256 + co);
        unsigned int w2 = *reinterpret_cast<const unsigned int*>(feat + (size_t)s2 * 256 + co);
        unsigned int w3 = *reinterpret_cast<const unsigned int*>(feat + (size_t)s3 * 256 + co);
        ax += bf2f((unsigned short)w0) + bf2f((unsigned short)w1)
            + bf2f((unsigned short)w2) + bf2f((unsigned short)w3);
        ay += bf2f((unsigned short)(w0 >> 16)) + bf2f((unsigned short)(w1 >> 16))
            + bf2f((unsigned short)(w2 >> 16)) + bf2f((unsigned short)(w3 >> 16));
    }
    for (; i < o1; ++i) {
        int s = csr[i];
        unsigned int w = *reinterpret_cast<const unsigned int*>(feat + (size_t)s * 256 + co);
        ax += bf2f((unsigned short)w);
        ay += bf2f((unsigned short)(w >> 16));
    }
    int deg = o1 - o0;
    float sc = (deg > 0) ? 1.0f / (float)deg : 0.0f;
    unsigned int outw = (unsigned int)f2bf(ax * sc) | ((unsigned int)f2bf(ay * sc) << 16);
    *reinterpret_cast<unsigned int*>(outp + co) = outw;
}

// ---------------------------------------------------------------------------
// MFMA finish, both directions by block range. IN-PLACE over A (row-aliased:
// bf16 [r][256] == fp32 [r][128] bytes; wave stores depend on all its loads,
// waves own disjoint rows).
// ---------------------------------------------------------------------------
#define NB_FIN 782   // ceil(50000/64)

__global__ __launch_bounds__(256) void finish2_kernel(
    const unsigned short* A_item, const unsigned short* A_user,
    const unsigned short* __restrict__ WfragUI, const unsigned short* __restrict__ WfragIU,
    const float* __restrict__ b_ui, const float* __restrict__ b_iu,
    float* out_item, float* out_user)
{
    const int b = blockIdx.x;
    const unsigned short *A, *Wfrag;
    const float* bias;
    float* outp;
    int rowBase;
    if (b < NB_FIN) { A = A_item; Wfrag = WfragUI; bias = b_ui; outp = out_item; rowBase = b * 64; }
    else { A = A_user; Wfrag = WfragIU; bias = b_iu; outp = out_user; rowBase = (b - NB_FIN) * 64; }

    const int tid  = threadIdx.x;
    const int wave = tid >> 6;
    const int lane = tid & 63;
    const int kg   = lane >> 4;
    rowBase += wave * 16;

    int arow = rowBase + (lane & 15);
    int arow_c = (arow < 50000) ? arow : 49999;
    const unsigned short* arow_ptr = A + (size_t)arow_c * 256 + kg * 8;

    f32x4 acc[8];
#pragma unroll
    for (int c = 0; c < 8; ++c) acc[c] = (f32x4){0.f, 0.f, 0.f, 0.f};

#pragma unroll
    for (int ks = 0; ks < 8; ++ks) {
        bf16x8 a = *reinterpret_cast<const bf16x8*>(arow_ptr + ks * 32);
        const unsigned short* bptr = Wfrag + ((size_t)(ks * 8) * 64 + lane) * 8;
#pragma unroll
        for (int c = 0; c < 8; ++c) {
            bf16x8 bb = *reinterpret_cast<const bf16x8*>(bptr + (size_t)c * 512);
            acc[c] = __builtin_amdgcn_mfma_f32_16x16x32_bf16(a, bb, acc[c], 0, 0, 0);
        }
    }

    const int orow0 = rowBase + kg * 4;
    const int ocol  = lane & 15;
#pragma unroll
    for (int c = 0; c < 8; ++c) {
        float bv = bias[c * 16 + ocol];
#pragma unroll
        for (int r = 0; r < 4; ++r) {
            int row = orow0 + r;
            if (row < 50000) outp[(size_t)row * 128 + c * 16 + ocol] = acc[c][r] + bv;
        }
    }
}

// ---------------------------------------------------------------------------
extern "C" void kernel_launch(void* const* d_in, const int* in_sizes, int n_in,
                              void* d_out, int out_size, void* d_ws, size_t ws_size,
                              hipStream_t stream) {
    const int*   user_ids = (const int*)d_in[0];
    const float* item_x   = (const float*)d_in[1];
    const int*   edge_ui  = (const int*)d_in[2];
    const int*   edge_iu  = (const int*)d_in[3];
    const float* user_emb = (const float*)d_in[4];
    const float* W_l_ui   = (const float*)d_in[5];
    const float* W_r_ui   = (const float*)d_in[6];
    const float* b_ui     = (const float*)d_in[7];
    const float* W_l_iu   = (const float*)d_in[8];
    const float* W_r_iu   = (const float*)d_in[9];
    const float* b_iu     = (const float*)d_in[10];

    // A matrices live inside d_out: bf16 [50000][256] == fp32 [50000][128] bytes.
    unsigned short* A_user = (unsigned short*)d_out;
    unsigned short* A_item = A_user + (size_t)N_USER * 256;
    float* out_user = (float*)d_out;
    float* out_item = out_user + (size_t)N_USER * D;

    // Workspace
    unsigned short* WfragUI = (unsigned short*)d_ws;        // 32768 ushorts
    unsigned short* WfragIU = WfragUI + 32768;              // 32768
    int* cnt  = (int*)(WfragIU + 32768);                    // NTOT
    int* off  = cnt + NTOT;                                 // NTOT+1
    int* cur  = off + NTOT + 1;                             // NTOT
    int* bsum = cur + NTOT;                                 // 256
    unsigned short* csr = (unsigned short*)(bsum + 256);    // NE2 (3.2MB)

    const int NB_SCAN = (NTOT + SCAN_BLK - 1) / SCAN_BLK;   // 196

    hipMemsetAsync(cnt, 0, NTOT * sizeof(int), stream);
    prep_kernel<<<PACKA_BLOCKS + COUNT_BLOCKS + PACKW_BLOCKS, 256, 0, stream>>>(
        user_emb, user_ids, item_x, edge_ui, edge_iu,
        W_l_ui, W_r_ui, W_l_iu, W_r_iu,
        A_user, A_item, cnt, WfragUI, WfragIU);

    partial_kernel<<<NB_SCAN, SCAN_BLK, 0, stream>>>(cnt, bsum, NTOT);
    scan_bsum_kernel<<<1, 256, 0, stream>>>(bsum, NB_SCAN);
    finalize_kernel<<<NB_SCAN, SCAN_BLK, 0, stream>>>(cnt, bsum, off, cur, NTOT);

    fill2_kernel<<<NE2 / 256, 256, 0, stream>>>(edge_ui, edge_iu, cur, csr);
    agg2_kernel<<<(NTOT * 64) / 256, 256, 0, stream>>>(A_user, A_item, off, csr);
    finish2_kernel<<<2 * NB_FIN, 256, 0, stream>>>(
        A_item, A_user, WfragUI, WfragIU, b_ui, b_iu, out_item, out_user);
}

// Round 6
// 163.678 us; speedup vs baseline: 17.6961x; 1.7840x over previous
//
#include <hip/hip_runtime.h>

#define N_USER 50000
#define N_ITEM 50000
#define N_EDGE 800000
#define D 128
#define NTOT   100000          // combined dst space: [0,50K)=items, [50K,100K)=users
#define NE2    1600000         // both directions' edges
#define BKT_SH 9               // 512 dsts per bucket
#define NBKT   196             // ceil(NTOT / 512)
#define CAP    12288           // LDS csr staging cap (bucket mean 8192, sigma ~90)

typedef __attribute__((ext_vector_type(8))) short     bf16x8;
typedef __attribute__((ext_vector_type(4))) float     f32x4;
typedef __attribute__((ext_vector_type(4))) unsigned short ushortx4;
typedef __attribute__((ext_vector_type(8))) unsigned short ushortx8;

__device__ __forceinline__ unsigned short f2bf(float f) {
    unsigned int u = __float_as_uint(f);
    unsigned int r = (u + 0x7fffu + ((u >> 16) & 1u)) >> 16;   // RNE
    return (unsigned short)r;
}
__device__ __forceinline__ float bf2f(unsigned short b) {
    return __uint_as_float(((unsigned int)b) << 16);
}

// ---------------------------------------------------------------------------
// PREP mega-kernel (block-range roles):
//  [0, 12500)         pack A tails: 100K rows x 32 lanes, fp32->bf16
//  [12500, 12891)     bucket-count: LDS-binned count of 1.6M edges -> gcnt[196]
//  [12891, 12923)     pack W frags (2 x 4096 ids)
// ---------------------------------------------------------------------------
#define PACKA_BLOCKS 12500
#define CNT_BLOCKS   391       // ceil(NE2 / 4096)
#define PACKW_BLOCKS 32

__global__ __launch_bounds__(256) void prep2_kernel(
    const float* __restrict__ user_emb, const int* __restrict__ user_ids,
    const float* __restrict__ item_x,
    const int* __restrict__ edge_ui, const int* __restrict__ edge_iu,
    const float* __restrict__ Wl_ui, const float* __restrict__ Wr_ui,
    const float* __restrict__ Wl_iu, const float* __restrict__ Wr_iu,
    unsigned short* A_user, unsigned short* A_item,
    int* gcnt, unsigned short* WfragUI, unsigned short* WfragIU)
{
    __shared__ int bcnt[NBKT];
    const int b = blockIdx.x;
    const int tid = threadIdx.x;

    if (b < PACKA_BLOCKS) {
        int gid = b * 256 + tid;
        int row = gid >> 5;
        int c = (gid & 31) << 2;
        const float* src;
        unsigned short* dst;
        if (row < N_USER) {
            src = user_emb + (size_t)user_ids[row] * D;
            dst = A_user + (size_t)row * 256 + 128;     // tail half
        } else {
            int r = row - N_USER;
            src = item_x + (size_t)r * D;
            dst = A_item + (size_t)r * 256 + 128;
        }
        const float4 v = *reinterpret_cast<const float4*>(src + c);
        ushortx4 o;
        o.x = f2bf(v.x); o.y = f2bf(v.y); o.z = f2bf(v.z); o.w = f2bf(v.w);
        *reinterpret_cast<ushortx4*>(dst + c) = o;
    } else if (b < PACKA_BLOCKS + CNT_BLOCKS) {
        for (int i = tid; i < NBKT; i += 256) bcnt[i] = 0;
        __syncthreads();
        int e0 = (b - PACKA_BLOCKS) * 4096;
#pragma unroll
        for (int j = 0; j < 16; ++j) {
            int e = e0 + j * 256 + tid;
            if (e < NE2) {
                int d = (e < N_EDGE) ? edge_ui[N_EDGE + e]
                                     : (N_ITEM + edge_iu[N_EDGE + (e - N_EDGE)]);
                atomicAdd(&bcnt[d >> BKT_SH], 1);
            }
        }
        __syncthreads();
        for (int i = tid; i < NBKT; i += 256)
            if (bcnt[i]) atomicAdd(&gcnt[i], bcnt[i]);
    } else {
        int id = (b - PACKA_BLOCKS - CNT_BLOCKS) * 256 + tid;   // [0, 8192)
        const float *Wl, *Wr;
        unsigned short* Wf;
        if (id < 4096) { Wl = Wl_ui; Wr = Wr_ui; Wf = WfragUI; }
        else { id -= 4096; Wl = Wl_iu; Wr = Wr_iu; Wf = WfragIU; }
        int lane = id & 63;
        int c    = (id >> 6) & 7;
        int ks   = id >> 9;
        int col  = c * 16 + (lane & 15);
        int k0   = ks * 32 + (lane >> 4) * 8;
        ushortx8 o;
#pragma unroll
        for (int i = 0; i < 8; ++i) {
            int k = k0 + i;
            float f = (k < D) ? Wl[(size_t)k * D + col] : Wr[(size_t)(k - D) * D + col];
            o[i] = f2bf(f);
        }
        *reinterpret_cast<ushortx8*>(Wf + (size_t)id * 8) = o;
    }
}

// ---------------------------------------------------------------------------
// Scan 196 bucket counts -> bucket bases; init bucket cursors.
// ---------------------------------------------------------------------------
__global__ __launch_bounds__(256) void bucketscan_kernel(
    const int* __restrict__ gcnt, int* __restrict__ bbase, int* __restrict__ bcur)
{
    __shared__ int s[256];
    int tid = threadIdx.x;
    int v = (tid < NBKT) ? gcnt[tid] : 0;
    s[tid] = v;
    __syncthreads();
    for (int d = 1; d < 256; d <<= 1) {
        int t = (tid >= d) ? s[tid - d] : 0;
        __syncthreads();
        s[tid] += t;
        __syncthreads();
    }
    if (tid < NBKT) {
        int base = s[tid] - v;     // exclusive
        bbase[tid] = base;
        bcur[tid]  = base;
    }
    if (tid == NBKT - 1) bbase[NBKT] = s[tid];
}

// ---------------------------------------------------------------------------
// Scatter records into bucket-segmented array. Record = src16 | dstlow9<<16.
// Per block: LDS bin-count, ONE chunk-reservation atomic per bucket, append.
// ---------------------------------------------------------------------------
#define B2_BLOCKS 98   // ceil(NE2 / 16384)

__global__ __launch_bounds__(1024) void scatter_records_kernel(
    const int* __restrict__ edge_ui, const int* __restrict__ edge_iu,
    int* __restrict__ bcur, unsigned int* __restrict__ records)
{
    __shared__ int bcnt[NBKT];
    __shared__ int bpos[NBKT];
    const int tid = threadIdx.x;
    for (int i = tid; i < NBKT; i += 1024) bcnt[i] = 0;
    __syncthreads();

    const int e0 = blockIdx.x * 16384;
    unsigned int rec[16];
    int bkt[16];
#pragma unroll
    for (int j = 0; j < 16; ++j) {
        int e = e0 + j * 1024 + tid;
        bkt[j] = -1;
        rec[j] = 0;
        if (e < NE2) {
            int s, d;
            if (e < N_EDGE) { s = edge_ui[e]; d = edge_ui[N_EDGE + e]; }
            else { int f = e - N_EDGE; s = edge_iu[f]; d = N_ITEM + edge_iu[N_EDGE + f]; }
            bkt[j] = d >> BKT_SH;
            rec[j] = (unsigned int)s | ((unsigned int)(d & 511) << 16);
            atomicAdd(&bcnt[bkt[j]], 1);
        }
    }
    __syncthreads();
    for (int i = tid; i < NBKT; i += 1024) {
        int c = bcnt[i];
        bpos[i] = c ? atomicAdd(&bcur[i], c) : 0;
    }
    __syncthreads();
#pragma unroll
    for (int j = 0; j < 16; ++j) {
        if (bkt[j] >= 0) {
            int p = atomicAdd(&bpos[bkt[j]], 1);
            records[p] = rec[j];
        }
    }
}

// ---------------------------------------------------------------------------
// Per-bucket CSR build: LDS counting-sort by dst within the bucket.
// Also writes off[] (global per-dst exclusive offsets) from the local scan.
// ---------------------------------------------------------------------------
__global__ __launch_bounds__(1024) void csr_build_kernel(
    const unsigned int* __restrict__ records, const int* __restrict__ bbase,
    unsigned short* __restrict__ csr, int* __restrict__ off)
{
    __shared__ int dcnt[512];
    __shared__ int sa[512], sb[512];
    __shared__ int dcur[512];
    __shared__ unsigned short stage[CAP];

    const int b    = blockIdx.x;
    const int tid  = threadIdx.x;
    const int base = bbase[b];
    const int nb   = bbase[b + 1] - base;

    if (tid < 512) dcnt[tid] = 0;
    __syncthreads();

    for (int i = tid; i < nb; i += 1024)
        atomicAdd(&dcnt[records[base + i] >> 16], 1);
    __syncthreads();

    // exclusive scan of dcnt[512] (Hillis-Steele, ping-pong)
    int* pa = sa; int* pb = sb;
    if (tid < 512) pa[tid] = dcnt[tid];
    __syncthreads();
    for (int d = 1; d < 512; d <<= 1) {
        if (tid < 512) pb[tid] = pa[tid] + ((tid >= d) ? pa[tid - d] : 0);
        __syncthreads();
        int* t = pa; pa = pb; pb = t;
    }
    if (tid < 512) {
        int excl = pa[tid] - dcnt[tid];
        dcur[tid] = excl;
        int dst = b * 512 + tid;
        if (dst < NTOT) off[dst] = base + excl;
    }
    if (b == NBKT - 1 && tid == 0) off[NTOT] = NE2;
    __syncthreads();

    if (nb <= CAP) {
        for (int i = tid; i < nb; i += 1024) {
            unsigned int r = records[base + i];
            int p = atomicAdd(&dcur[r >> 16], 1);
            stage[p] = (unsigned short)r;
        }
        __syncthreads();
        for (int i = tid; i < nb; i += 1024) csr[base + i] = stage[i];
    } else {
        // structurally impossible for this dataset; correctness fallback
        for (int i = tid; i < nb; i += 1024) {
            unsigned int r = records[base + i];
            int p = atomicAdd(&dcur[r >> 16], 1);
            csr[base + p] = (unsigned short)r;
        }
    }
}

// ---------------------------------------------------------------------------
// Aggregate (mean) both directions: one 64-lane wave per combined dst row.
// ---------------------------------------------------------------------------
__global__ __launch_bounds__(256) void agg2_kernel(
    unsigned short* A_user, unsigned short* A_item,
    const int* __restrict__ off, const unsigned short* __restrict__ csr)
{
    int r = (blockIdx.x * blockDim.x + threadIdx.x) >> 6;
    if (r >= NTOT) return;
    const int lane = threadIdx.x & 63;
    const unsigned short* feat;
    unsigned short* outp;
    if (r < N_ITEM) { feat = A_user + 128; outp = A_item + (size_t)r * 256; }
    else            { feat = A_item + 128; outp = A_user + (size_t)(r - N_ITEM) * 256; }

    const int o0 = off[r], o1 = off[r + 1];
    const int co = lane * 2;
    float ax = 0.f, ay = 0.f;
    int i = o0;
    for (; i + 3 < o1; i += 4) {
        int s0 = csr[i], s1 = csr[i + 1], s2 = csr[i + 2], s3 = csr[i + 3];
        unsigned int w0 = *reinterpret_cast<const unsigned int*>(feat + (size_t)s0 * 256 + co);
        unsigned int w1 = *reinterpret_cast<const unsigned int*>(feat + (size_t)s1 * 256 + co);
        unsigned int w2 = *reinterpret_cast<const unsigned int*>(feat + (size_t)s2 * 256 + co);
        unsigned int w3 = *reinterpret_cast<const unsigned int*>(feat + (size_t)s3 * 256 + co);
        ax += bf2f((unsigned short)w0) + bf2f((unsigned short)w1)
            + bf2f((unsigned short)w2) + bf2f((unsigned short)w3);
        ay += bf2f((unsigned short)(w0 >> 16)) + bf2f((unsigned short)(w1 >> 16))
            + bf2f((unsigned short)(w2 >> 16)) + bf2f((unsigned short)(w3 >> 16));
    }
    for (; i < o1; ++i) {
        int s = csr[i];
        unsigned int w = *reinterpret_cast<const unsigned int*>(feat + (size_t)s * 256 + co);
        ax += bf2f((unsigned short)w);
        ay += bf2f((unsigned short)(w >> 16));
    }
    int deg = o1 - o0;
    float sc = (deg > 0) ? 1.0f / (float)deg : 0.0f;
    unsigned int outw = (unsigned int)f2bf(ax * sc) | ((unsigned int)f2bf(ay * sc) << 16);
    *reinterpret_cast<unsigned int*>(outp + co) = outw;
}

// ---------------------------------------------------------------------------
// MFMA finish, both directions by block range. IN-PLACE over A (row-aliased:
// bf16 [r][256] == fp32 [r][128] bytes; wave stores depend on all its loads,
// waves own disjoint rows).
// ---------------------------------------------------------------------------
#define NB_FIN 782   // ceil(50000/64)

__global__ __launch_bounds__(256) void finish2_kernel(
    const unsigned short* A_item, const unsigned short* A_user,
    const unsigned short* __restrict__ WfragUI, const unsigned short* __restrict__ WfragIU,
    const float* __restrict__ b_ui, const float* __restrict__ b_iu,
    float* out_item, float* out_user)
{
    const int b = blockIdx.x;
    const unsigned short *A, *Wfrag;
    const float* bias;
    float* outp;
    int rowBase;
    if (b < NB_FIN) { A = A_item; Wfrag = WfragUI; bias = b_ui; outp = out_item; rowBase = b * 64; }
    else { A = A_user; Wfrag = WfragIU; bias = b_iu; outp = out_user; rowBase = (b - NB_FIN) * 64; }

    const int tid  = threadIdx.x;
    const int wave = tid >> 6;
    const int lane = tid & 63;
    const int kg   = lane >> 4;
    rowBase += wave * 16;

    int arow = rowBase + (lane & 15);
    int arow_c = (arow < 50000) ? arow : 49999;
    const unsigned short* arow_ptr = A + (size_t)arow_c * 256 + kg * 8;

    f32x4 acc[8];
#pragma unroll
    for (int c = 0; c < 8; ++c) acc[c] = (f32x4){0.f, 0.f, 0.f, 0.f};

#pragma unroll
    for (int ks = 0; ks < 8; ++ks) {
        bf16x8 a = *reinterpret_cast<const bf16x8*>(arow_ptr + ks * 32);
        const unsigned short* bptr = Wfrag + ((size_t)(ks * 8) * 64 + lane) * 8;
#pragma unroll
        for (int c = 0; c < 8; ++c) {
            bf16x8 bb = *reinterpret_cast<const bf16x8*>(bptr + (size_t)c * 512);
            acc[c] = __builtin_amdgcn_mfma_f32_16x16x32_bf16(a, bb, acc[c], 0, 0, 0);
        }
    }

    const int orow0 = rowBase + kg * 4;
    const int ocol  = lane & 15;
#pragma unroll
    for (int c = 0; c < 8; ++c) {
        float bv = bias[c * 16 + ocol];
#pragma unroll
        for (int r = 0; r < 4; ++r) {
            int row = orow0 + r;
            if (row < 50000) outp[(size_t)row * 128 + c * 16 + ocol] = acc[c][r] + bv;
        }
    }
}

// ---------------------------------------------------------------------------
extern "C" void kernel_launch(void* const* d_in, const int* in_sizes, int n_in,
                              void* d_out, int out_size, void* d_ws, size_t ws_size,
                              hipStream_t stream) {
    const int*   user_ids = (const int*)d_in[0];
    const float* item_x   = (const float*)d_in[1];
    const int*   edge_ui  = (const int*)d_in[2];
    const int*   edge_iu  = (const int*)d_in[3];
    const float* user_emb = (const float*)d_in[4];
    const float* W_l_ui   = (const float*)d_in[5];
    const float* W_r_ui   = (const float*)d_in[6];
    const float* b_ui     = (const float*)d_in[7];
    const float* W_l_iu   = (const float*)d_in[8];
    const float* W_r_iu   = (const float*)d_in[9];
    const float* b_iu     = (const float*)d_in[10];

    // A matrices live inside d_out: bf16 [50000][256] == fp32 [50000][128] bytes.
    unsigned short* A_user = (unsigned short*)d_out;
    unsigned short* A_item = A_user + (size_t)N_USER * 256;
    float* out_user = (float*)d_out;
    float* out_item = out_user + (size_t)N_USER * D;

    // Workspace
    unsigned short* WfragUI = (unsigned short*)d_ws;        // 32768 u16 (64KB)
    unsigned short* WfragIU = WfragUI + 32768;              // 32768 u16
    int* gcnt  = (int*)(WfragIU + 32768);                   // NBKT
    int* bbase = gcnt + NBKT;                               // NBKT+1
    int* bcur  = bbase + NBKT + 1;                          // NBKT
    int* off   = bcur + NBKT;                               // NTOT+1
    unsigned int*   records = (unsigned int*)(off + NTOT + 1);   // NE2 (6.4MB)
    unsigned short* csr     = (unsigned short*)(records + NE2);  // NE2 (3.2MB)

    hipMemsetAsync(gcnt, 0, NBKT * sizeof(int), stream);

    prep2_kernel<<<PACKA_BLOCKS + CNT_BLOCKS + PACKW_BLOCKS, 256, 0, stream>>>(
        user_emb, user_ids, item_x, edge_ui, edge_iu,
        W_l_ui, W_r_ui, W_l_iu, W_r_iu,
        A_user, A_item, gcnt, WfragUI, WfragIU);

    bucketscan_kernel<<<1, 256, 0, stream>>>(gcnt, bbase, bcur);
    scatter_records_kernel<<<B2_BLOCKS, 1024, 0, stream>>>(edge_ui, edge_iu, bcur, records);
    csr_build_kernel<<<NBKT, 1024, 0, stream>>>(records, bbase, csr, off);

    agg2_kernel<<<(NTOT * 64) / 256, 256, 0, stream>>>(A_user, A_item, off, csr);
    finish2_kernel<<<2 * NB_FIN, 256, 0, stream>>>(
        A_item, A_user, WfragUI, WfragIU, b_ui, b_iu, out_item, out_user);
}